// Round 1
// baseline (1489.631 us; speedup 1.0000x reference)
//
#include <hip/hip_runtime.h>
#include <cstdint>
#include <cstddef>

#define D 128

// swizzled LDS float index for a [rows][128] tile: XOR 16B-group by (row&7)
// keeps float4 alignment; spreads bank groups so strided-row ds_read_b128 is ~2-way (free).
__device__ __forceinline__ int swz(int r, int k) { return r * D + (k ^ ((r & 7) << 2)); }

// ---------------- K0: fold weights on device ----------------
// Bcat[640][128]: rows 0..127   = Wq^T            (q = x@Wq)
//                 rows 128..255 = Wk^T            (k = x@Wk)
//                 rows 256..383 = (Wv@Wl^T)^T     (vW = v@Wl^T)
//                 rows 384..511 = Wl              (xW = x@Wl^T)
//                 rows 512..639 = 0.6*(Wl@Wg)     (u  = 0.6*(x@Wg^T)@Wl^T)
// biasout[o] = bl[o] + 0.6*sum_m bg[m]*Wl[o][m]
__global__ void k_prep(const float* __restrict__ Wq, const float* __restrict__ Wk,
                       const float* __restrict__ Wv, const float* __restrict__ Wg,
                       const float* __restrict__ bg, const float* __restrict__ Wl,
                       const float* __restrict__ bl,
                       float* __restrict__ Bcat, float* __restrict__ biasout)
{
    const int b = blockIdx.x;
    const int t = threadIdx.x; // 128
    if (b < 640) {
        const int strip = b >> 7, n = b & 127;
        float val;
        if (strip == 0) {
            val = Wq[t * D + n];
        } else if (strip == 1) {
            val = Wk[t * D + n];
        } else if (strip == 2) {
            float s = 0.f;
            for (int m = 0; m < D; ++m) s += Wv[t * D + m] * Wl[n * D + m];
            val = s;
        } else if (strip == 3) {
            val = Wl[n * D + t];
        } else {
            float s = 0.f;
            for (int m = 0; m < D; ++m) s += Wl[n * D + m] * Wg[m * D + t];
            val = 0.6f * s;
        }
        Bcat[(size_t)b * D + t] = val;
    } else {
        float s = 0.f;
        for (int m = 0; m < D; ++m) s += bg[m] * Wl[t * D + m];
        biasout[t] = bl[t] + 0.6f * s;
    }
}

__global__ void k_zero(float* __restrict__ stats, float* __restrict__ ksum)
{
    const int t = threadIdx.x;
    if (t < 8) stats[t] = 0.f;
    if (t < D) ksum[t] = 0.f;
}

__global__ void k_initdeg(float* __restrict__ deg, int M)
{
    const int i = blockIdx.x * 256 + threadIdx.x;
    if (i < M) deg[i] = 1.0f; // self loop
}

__global__ void k_deg(const int* __restrict__ dst, float* __restrict__ deg, int E)
{
    const int e = blockIdx.x * 256 + threadIdx.x;
    if (e < E) unsafeAtomicAdd(&deg[dst[e]], 1.0f);
}

__global__ void k_dinv(const float* __restrict__ deg, float* __restrict__ dinv, int M)
{
    const int i = blockIdx.x * 256 + threadIdx.x;
    if (i < M) dinv[i] = rsqrtf(deg[i]);
}

// ---------------- K1: x[M,128] @ Bcat^T -> 5 outputs [M,128] each ----------------
// tile 64 rows x 64 cols, K=128 (whole), 256 threads, 4x4 micro-tile (strided).
__global__ __launch_bounds__(256) void k_gemm5(const float* __restrict__ x,
                                               const float* __restrict__ Bcat,
                                               float* __restrict__ outbase,
                                               int M, size_t NQ)
{
    __shared__ float As[64 * D];
    __shared__ float Bs[64 * D];
    const int t = threadIdx.x;
    const int row0 = blockIdx.x * 64;
    const int n0 = blockIdx.y * 64; // global col among 640

    for (int s = 0; s < 8; ++s) {
        int f = t + 256 * s;
        int r = f >> 5, k0 = (f & 31) << 2;
        int gr = row0 + r; if (gr > M - 1) gr = M - 1;
        *(float4*)(As + swz(r, k0)) = *(const float4*)(x + (size_t)gr * D + k0);
    }
    for (int s = 0; s < 8; ++s) {
        int f = t + 256 * s;
        int r = f >> 5, k0 = (f & 31) << 2;
        *(float4*)(Bs + swz(r, k0)) = *(const float4*)(Bcat + (size_t)(n0 + r) * D + k0);
    }
    __syncthreads();

    const int tx = t & 15, ty = t >> 4;
    float acc[4][4];
#pragma unroll
    for (int i = 0; i < 4; ++i)
#pragma unroll
        for (int j = 0; j < 4; ++j) acc[i][j] = 0.f;

#pragma unroll 2
    for (int k0 = 0; k0 < D; k0 += 4) {
        float4 a[4], b[4];
#pragma unroll
        for (int i = 0; i < 4; ++i) a[i] = *(const float4*)(As + swz(ty + 16 * i, k0));
#pragma unroll
        for (int j = 0; j < 4; ++j) b[j] = *(const float4*)(Bs + swz(tx + 16 * j, k0));
#pragma unroll
        for (int i = 0; i < 4; ++i) {
            const float av[4] = {a[i].x, a[i].y, a[i].z, a[i].w};
#pragma unroll
            for (int j = 0; j < 4; ++j) {
                acc[i][j] += av[0] * b[j].x + av[1] * b[j].y + av[2] * b[j].z + av[3] * b[j].w;
            }
        }
    }

    const int mat = n0 >> 7, col0 = n0 & 127;
    float* outp = outbase + (size_t)mat * NQ;
#pragma unroll
    for (int i = 0; i < 4; ++i) {
        const int r = row0 + ty + 16 * i;
        if (r < M) {
#pragma unroll
            for (int j = 0; j < 4; ++j)
                outp[(size_t)r * D + col0 + tx + 16 * j] = acc[i][j];
        }
    }
}

// ---------------- K1b: sumsq(q), sumsq(k), colsum(k) ----------------
__global__ __launch_bounds__(256) void k_stats(const float* __restrict__ qarr,
                                               const float* __restrict__ karr,
                                               float* __restrict__ stats,
                                               float* __restrict__ ksum, size_t NQ)
{
    __shared__ float lks[D];
    const int t = threadIdx.x;
    if (t < D) lks[t] = 0.f;
    __syncthreads();
    float sq = 0.f, sk = 0.f, kc = 0.f;
    const size_t stride = (size_t)gridDim.x * 256; // multiple of 128
    for (size_t i = (size_t)blockIdx.x * 256 + t; i < NQ; i += stride) {
        const float qv = qarr[i]; sq += qv * qv;
        const float kv = karr[i]; sk += kv * kv; kc += kv;
    }
    atomicAdd(&lks[t & 127], kc);
    for (int off = 32; off > 0; off >>= 1) {
        sq += __shfl_down(sq, off);
        sk += __shfl_down(sk, off);
    }
    __syncthreads();
    if ((t & 63) == 0) { unsafeAtomicAdd(&stats[0], sq); unsafeAtomicAdd(&stats[1], sk); }
    if (t < D) unsafeAtomicAdd(&ksum[t], lks[t]);
}

// ---------------- K2: split-K partials of C = k^T @ vW  (128x128, K=M) ----------------
__global__ __launch_bounds__(256) void k_ktv(const float* __restrict__ karr,
                                             const float* __restrict__ vW,
                                             float* __restrict__ part, int M)
{
    __shared__ float ks[4][D];
    __shared__ float vs[4][D];
    const int t = threadIdx.x;
    const int P = (int)gridDim.x;
    const int chunk = (M + P - 1) / P;
    const int rbeg = blockIdx.x * chunk;
    const int rend = min(rbeg + chunk, M);
    const int tj = t & 15, to = t >> 4;
    float acc[4][4];
#pragma unroll
    for (int i = 0; i < 4; ++i)
#pragma unroll
        for (int j = 0; j < 4; ++j) acc[i][j] = 0.f;

    for (int r0 = rbeg; r0 < rend; r0 += 4) {
        const int rr = t >> 6, c = t & 63;
        const int gr = r0 + rr;
        if (c < 32) {
            float4 v4 = make_float4(0.f, 0.f, 0.f, 0.f);
            if (gr < rend) v4 = *(const float4*)(karr + (size_t)gr * D + c * 4);
            *(float4*)(&ks[rr][c * 4]) = v4;
        } else {
            const int cc = c - 32;
            float4 v4 = make_float4(0.f, 0.f, 0.f, 0.f);
            if (gr < rend) v4 = *(const float4*)(vW + (size_t)gr * D + cc * 4);
            *(float4*)(&vs[rr][cc * 4]) = v4;
        }
        __syncthreads();
#pragma unroll
        for (int r2 = 0; r2 < 4; ++r2) {
            const float4 a = *(const float4*)(&ks[r2][4 * tj]);
            const float4 b = *(const float4*)(&vs[r2][4 * to]);
            const float av[4] = {a.x, a.y, a.z, a.w};
            const float bv[4] = {b.x, b.y, b.z, b.w};
#pragma unroll
            for (int jj = 0; jj < 4; ++jj)
#pragma unroll
                for (int oo = 0; oo < 4; ++oo) acc[jj][oo] += av[jj] * bv[oo];
        }
        __syncthreads();
    }
    float* pp = part + (size_t)blockIdx.x * (D * D);
#pragma unroll
    for (int jj = 0; jj < 4; ++jj)
#pragma unroll
        for (int oo = 0; oo < 4; ++oo)
            pp[(size_t)(4 * tj + jj) * D + 4 * to + oo] = acc[jj][oo];
}

__global__ void k_redC(const float* __restrict__ part, float* __restrict__ Craw, int P)
{
    const int e = blockIdx.x * 256 + threadIdx.x; // 16384 total
    float s = 0.f;
    for (int p = 0; p < P; ++p) s += part[(size_t)p * (D * D) + e];
    Craw[e] = s;
}

__global__ void k_scal(const float* __restrict__ ksum, float* __restrict__ stats,
                       float* __restrict__ kq)
{
    const int t = threadIdx.x; // 128
    const float nq = sqrtf(stats[0]);
    const float nk = sqrtf(stats[1]);
    const float inv = 1.0f / (nq * nk * 128.0f);
    kq[t] = ksum[t] * inv;
    if (t == 0) stats[2] = inv;
}

__global__ void k_c3t(const float* __restrict__ Craw, const float* __restrict__ stats,
                      float* __restrict__ C3t)
{
    const int e = blockIdx.x * 256 + threadIdx.x; // 16384, e = o*128 + j
    C3t[e] = Craw[(size_t)(e & 127) * D + (e >> 7)] * stats[2];
}

// ---------------- K4: per-node epilogue: out = 0.16*scale*(vW + q@C3^T) + 0.24*xW + bias + u/deg ----------------
__global__ __launch_bounds__(256) void k_final(const float* __restrict__ qarr,
                                               const float* __restrict__ C3t,
                                               const float* __restrict__ kq,
                                               const float* __restrict__ vW,
                                               const float* __restrict__ xW,
                                               const float* __restrict__ uarr,
                                               const float* __restrict__ deg,
                                               const float* __restrict__ biasout,
                                               float* __restrict__ out, int M)
{
    __shared__ float As[64 * D];
    __shared__ float Bs[64 * D];
    __shared__ float qks[64][4];
    __shared__ float rowcoef[64];
    __shared__ float selfc[64];
    const int t = threadIdx.x;
    const int row0 = blockIdx.x * 64;
    const int col0 = blockIdx.y * 64;

    for (int s = 0; s < 8; ++s) {
        int f = t + 256 * s;
        int r = f >> 5, k0 = (f & 31) << 2;
        int gr = row0 + r; if (gr > M - 1) gr = M - 1;
        *(float4*)(As + swz(r, k0)) = *(const float4*)(qarr + (size_t)gr * D + k0);
    }
    for (int s = 0; s < 8; ++s) {
        int f = t + 256 * s;
        int r = f >> 5, k0 = (f & 31) << 2;
        *(float4*)(Bs + swz(r, k0)) = *(const float4*)(C3t + (size_t)(col0 + r) * D + k0);
    }
    __syncthreads();

    // per-row qk = q[r] . kq
    {
        const int rr = t >> 2, part = t & 3;
        float s = 0.f;
        for (int k = part * 32; k < part * 32 + 32; ++k) s += As[swz(rr, k)] * kq[k];
        qks[rr][part] = s;
    }
    __syncthreads();
    if (t < 64) {
        const float qk = qks[t][0] + qks[t][1] + qks[t][2] + qks[t][3];
        rowcoef[t] = 0.16f / (1.0f + qk);
        const int r = row0 + t;
        selfc[t] = (r < M) ? (1.0f / deg[r]) : 0.f;
    }
    __syncthreads();

    const int tx = t & 15, ty = t >> 4;
    float acc[4][4];
#pragma unroll
    for (int i = 0; i < 4; ++i)
#pragma unroll
        for (int j = 0; j < 4; ++j) acc[i][j] = 0.f;

#pragma unroll 2
    for (int k0 = 0; k0 < D; k0 += 4) {
        float4 a[4], b[4];
#pragma unroll
        for (int i = 0; i < 4; ++i) a[i] = *(const float4*)(As + swz(ty + 16 * i, k0));
#pragma unroll
        for (int j = 0; j < 4; ++j) b[j] = *(const float4*)(Bs + swz(tx + 16 * j, k0));
#pragma unroll
        for (int i = 0; i < 4; ++i) {
            const float av[4] = {a[i].x, a[i].y, a[i].z, a[i].w};
#pragma unroll
            for (int j = 0; j < 4; ++j) {
                acc[i][j] += av[0] * b[j].x + av[1] * b[j].y + av[2] * b[j].z + av[3] * b[j].w;
            }
        }
    }

#pragma unroll
    for (int i = 0; i < 4; ++i) {
        const int rr = ty + 16 * i;
        const int r = row0 + rr;
        if (r < M) {
            const float rc = rowcoef[rr], sc = selfc[rr];
#pragma unroll
            for (int j = 0; j < 4; ++j) {
                const int c = col0 + tx + 16 * j;
                const size_t idx = (size_t)r * D + c;
                out[idx] = rc * (vW[idx] + acc[i][j]) + 0.24f * xW[idx] + biasout[c] + sc * uarr[idx];
            }
        }
    }
}

// ---------------- K5: edge scatter: out[dst] += dinv[s]*dinv[d] * u[src] ----------------
__global__ __launch_bounds__(256) void k_scatter(const int* __restrict__ src,
                                                 const int* __restrict__ dst,
                                                 const float* __restrict__ dinv,
                                                 const float* __restrict__ uarr,
                                                 float* __restrict__ out, int E)
{
    const size_t total = (size_t)E * 32;
    const size_t stride = (size_t)gridDim.x * 256;
    for (size_t task = (size_t)blockIdx.x * 256 + threadIdx.x; task < total; task += stride) {
        const int e = (int)(task >> 5), sub = (int)(task & 31);
        const int s = src[e], d = dst[e];
        const float w = dinv[s] * dinv[d];
        const float4 uv = *(const float4*)(uarr + (size_t)s * D + sub * 4);
        float* o = out + (size_t)d * D + sub * 4;
        unsafeAtomicAdd(o + 0, w * uv.x);
        unsafeAtomicAdd(o + 1, w * uv.y);
        unsafeAtomicAdd(o + 2, w * uv.z);
        unsafeAtomicAdd(o + 3, w * uv.w);
    }
}

extern "C" void kernel_launch(void* const* d_in, const int* in_sizes, int n_in,
                              void* d_out, int out_size, void* d_ws, size_t ws_size,
                              hipStream_t stream)
{
    const float* x  = (const float*)d_in[0];
    const int*   ei = (const int*)d_in[1];
    const float* Wq = (const float*)d_in[2];
    const float* Wk = (const float*)d_in[3];
    const float* Wv = (const float*)d_in[4];
    const float* Wg = (const float*)d_in[5];
    const float* bg = (const float*)d_in[6];
    const float* Wl = (const float*)d_in[7];
    const float* bl = (const float*)d_in[8];

    const int M = in_sizes[0] / D;
    const int E = in_sizes[1] / 2;
    const size_t NQ = (size_t)M * D;

    float* ws      = (float*)d_ws;
    float* q       = ws;                 // [M,128]
    float* karr    = ws + NQ;            // [M,128]
    float* vW      = ws + 2 * NQ;        // [M,128]
    float* xW      = ws + 3 * NQ;        // [M,128]
    float* u       = ws + 4 * NQ;        // [M,128]
    float* deg     = ws + 5 * NQ;        // [M]
    float* dinv    = deg + M;            // [M]
    float* stats   = dinv + M;           // [8]: sumsq_q, sumsq_k, inv
    float* ksum    = stats + 8;          // [128]
    float* kq      = ksum + D;           // [128]
    float* Craw    = kq + D;             // [128*128]
    float* C3t     = Craw + D * D;       // [128*128]
    float* Bcat    = C3t + D * D;        // [640*128]
    float* biasout = Bcat + 640 * D;     // [128]
    float* part    = biasout + D;        // [P*128*128]
    const int P = 512;

    float* out = (float*)d_out;

    k_prep<<<dim3(641), dim3(128), 0, stream>>>(Wq, Wk, Wv, Wg, bg, Wl, bl, Bcat, biasout);
    k_zero<<<1, 256, 0, stream>>>(stats, ksum);
    k_initdeg<<<(M + 255) / 256, 256, 0, stream>>>(deg, M);
    k_deg<<<(E + 255) / 256, 256, 0, stream>>>(ei + E, deg, E);
    k_dinv<<<(M + 255) / 256, 256, 0, stream>>>(deg, dinv, M);

    k_gemm5<<<dim3((M + 63) / 64, 10), 256, 0, stream>>>(x, Bcat, q, M, NQ);
    k_stats<<<512, 256, 0, stream>>>(q, karr, stats, ksum, NQ);
    k_ktv<<<P, 256, 0, stream>>>(karr, vW, part, M);
    k_redC<<<64, 256, 0, stream>>>(part, Craw, P);
    k_scal<<<1, 128, 0, stream>>>(ksum, stats, kq);
    k_c3t<<<64, 256, 0, stream>>>(Craw, stats, C3t);

    k_final<<<dim3((M + 63) / 64, 2), 256, 0, stream>>>(q, C3t, kq, vW, xW, u, deg, biasout, out, M);
    k_scatter<<<4096, 256, 0, stream>>>(ei, ei + E, dinv, u, out, E);
}

// Round 2
// 615.260 us; speedup vs baseline: 2.4211x; 2.4211x over previous
//
#include <hip/hip_runtime.h>
#include <cstdint>
#include <cstddef>

#define D 128

// swizzled LDS float index for a [rows][128] tile: XOR 16B-group by (row&7)
__device__ __forceinline__ int swz(int r, int k) { return r * D + (k ^ ((r & 7) << 2)); }

// ---------------- K0: fold weights on device ----------------
// Bcat[640][128]: rows 0..127   = Wq^T            (q = x@Wq)
//                 rows 128..255 = Wk^T            (k = x@Wk)
//                 rows 256..383 = (Wv@Wl^T)^T     (vW = v@Wl^T)
//                 rows 384..511 = Wl              (xW = x@Wl^T)
//                 rows 512..639 = 0.6*(Wl@Wg)     (u  = 0.6*(x@Wg^T)@Wl^T)
// biasout[o] = bl[o] + 0.6*sum_m bg[m]*Wl[o][m]
__global__ void k_prep(const float* __restrict__ Wq, const float* __restrict__ Wk,
                       const float* __restrict__ Wv, const float* __restrict__ Wg,
                       const float* __restrict__ bg, const float* __restrict__ Wl,
                       const float* __restrict__ bl,
                       float* __restrict__ Bcat, float* __restrict__ biasout)
{
    const int b = blockIdx.x;
    const int t = threadIdx.x; // 128
    if (b < 640) {
        const int strip = b >> 7, n = b & 127;
        float val;
        if (strip == 0) {
            val = Wq[t * D + n];
        } else if (strip == 1) {
            val = Wk[t * D + n];
        } else if (strip == 2) {
            float s = 0.f;
            for (int m = 0; m < D; ++m) s += Wv[t * D + m] * Wl[n * D + m];
            val = s;
        } else if (strip == 3) {
            val = Wl[n * D + t];
        } else {
            float s = 0.f;
            for (int m = 0; m < D; ++m) s += Wl[n * D + m] * Wg[m * D + t];
            val = 0.6f * s;
        }
        Bcat[(size_t)b * D + t] = val;
    } else {
        float s = 0.f;
        for (int m = 0; m < D; ++m) s += bg[m] * Wl[t * D + m];
        biasout[t] = bl[t] + 0.6f * s;
    }
}

__global__ void k_zero(float* __restrict__ stats, float* __restrict__ ksum)
{
    const int t = threadIdx.x;
    if (t < 8) stats[t] = 0.f;
    if (t < D) ksum[t] = 0.f;
}

__global__ void k_zcnt(int* __restrict__ cnt, int M)
{
    const int i = blockIdx.x * 256 + threadIdx.x;
    if (i < M) cnt[i] = 0;
}

__global__ void k_hist(const int* __restrict__ dst, int* __restrict__ cnt, int E)
{
    const int e = blockIdx.x * 256 + threadIdx.x;
    if (e < E) atomicAdd(&cnt[dst[e]], 1);
}

__global__ void k_dinv(const int* __restrict__ cnt, float* __restrict__ dinv, int M)
{
    const int i = blockIdx.x * 256 + threadIdx.x;
    if (i < M) dinv[i] = rsqrtf((float)(cnt[i] + 1)); // +1 self loop
}

// single-block exclusive scan over cnt -> offs (M up to a few hundred k)
__global__ __launch_bounds__(1024) void k_scan(const int* __restrict__ cnt,
                                               int* __restrict__ offs, int M)
{
    __shared__ int wsum[16];
    __shared__ int carry_s;
    const int t = threadIdx.x;
    const int lane = t & 63, w = t >> 6;
    if (t == 0) carry_s = 0;
    __syncthreads();
    for (int base = 0; base < M; base += 1024) {
        const int i = base + t;
        const int v = (i < M) ? cnt[i] : 0;
        int s = v;
        for (int off = 1; off < 64; off <<= 1) {
            int n = __shfl_up(s, off);
            if (lane >= off) s += n;
        }
        if (lane == 63) wsum[w] = s;
        __syncthreads();
        if (w == 0 && lane < 16) {
            int ss = wsum[lane];
            for (int off = 1; off < 16; off <<= 1) {
                int n = __shfl_up(ss, off);
                if (lane >= off) ss += n;
            }
            wsum[lane] = ss;
        }
        __syncthreads();
        const int waveoff = (w == 0) ? 0 : wsum[w - 1];
        const int carry = carry_s;
        if (i < M) offs[i] = carry + waveoff + s - v;
        __syncthreads();
        if (t == 1023) carry_s = carry + wsum[15];
        __syncthreads();
    }
}

// fill CSR: pos = offs[d]++ (after this kernel offs[d] == segment END)
__global__ void k_fill(const int* __restrict__ src, const int* __restrict__ dst,
                       const float* __restrict__ dinv,
                       int* __restrict__ offs, int* __restrict__ csrc,
                       float* __restrict__ cw, int E)
{
    const int e = blockIdx.x * 256 + threadIdx.x;
    if (e < E) {
        const int s = src[e], d = dst[e];
        const int pos = atomicAdd(&offs[d], 1);
        csrc[pos] = s;
        cw[pos] = dinv[s] * dinv[d];
    }
}

// ---------------- K1: x[M,128] @ Bcat^T -> 5 outputs [M,128] each ----------------
__global__ __launch_bounds__(256) void k_gemm5(const float* __restrict__ x,
                                               const float* __restrict__ Bcat,
                                               float* __restrict__ outbase,
                                               int M, size_t NQ)
{
    __shared__ float As[64 * D];
    __shared__ float Bs[64 * D];
    const int t = threadIdx.x;
    const int row0 = blockIdx.x * 64;
    const int n0 = blockIdx.y * 64; // global col among 640

    for (int s = 0; s < 8; ++s) {
        int f = t + 256 * s;
        int r = f >> 5, k0 = (f & 31) << 2;
        int gr = row0 + r; if (gr > M - 1) gr = M - 1;
        *(float4*)(As + swz(r, k0)) = *(const float4*)(x + (size_t)gr * D + k0);
    }
    for (int s = 0; s < 8; ++s) {
        int f = t + 256 * s;
        int r = f >> 5, k0 = (f & 31) << 2;
        *(float4*)(Bs + swz(r, k0)) = *(const float4*)(Bcat + (size_t)(n0 + r) * D + k0);
    }
    __syncthreads();

    const int tx = t & 15, ty = t >> 4;
    float acc[4][4];
#pragma unroll
    for (int i = 0; i < 4; ++i)
#pragma unroll
        for (int j = 0; j < 4; ++j) acc[i][j] = 0.f;

#pragma unroll 2
    for (int k0 = 0; k0 < D; k0 += 4) {
        float4 a[4], b[4];
#pragma unroll
        for (int i = 0; i < 4; ++i) a[i] = *(const float4*)(As + swz(ty + 16 * i, k0));
#pragma unroll
        for (int j = 0; j < 4; ++j) b[j] = *(const float4*)(Bs + swz(tx + 16 * j, k0));
#pragma unroll
        for (int i = 0; i < 4; ++i) {
            const float av[4] = {a[i].x, a[i].y, a[i].z, a[i].w};
#pragma unroll
            for (int j = 0; j < 4; ++j) {
                acc[i][j] += av[0] * b[j].x + av[1] * b[j].y + av[2] * b[j].z + av[3] * b[j].w;
            }
        }
    }

    const int mat = n0 >> 7, col0 = n0 & 127;
    float* outp = outbase + (size_t)mat * NQ;
#pragma unroll
    for (int i = 0; i < 4; ++i) {
        const int r = row0 + ty + 16 * i;
        if (r < M) {
#pragma unroll
            for (int j = 0; j < 4; ++j)
                outp[(size_t)r * D + col0 + tx + 16 * j] = acc[i][j];
        }
    }
}

// ---------------- K1b: sumsq(q), sumsq(k), colsum(k) ----------------
__global__ __launch_bounds__(256) void k_stats(const float* __restrict__ qarr,
                                               const float* __restrict__ karr,
                                               float* __restrict__ stats,
                                               float* __restrict__ ksum, size_t NQ)
{
    __shared__ float lks[D];
    const int t = threadIdx.x;
    if (t < D) lks[t] = 0.f;
    __syncthreads();
    float sq = 0.f, sk = 0.f, kc = 0.f;
    const size_t stride = (size_t)gridDim.x * 256; // multiple of 128
    for (size_t i = (size_t)blockIdx.x * 256 + t; i < NQ; i += stride) {
        const float qv = qarr[i]; sq += qv * qv;
        const float kv = karr[i]; sk += kv * kv; kc += kv;
    }
    atomicAdd(&lks[t & 127], kc);
    for (int off = 32; off > 0; off >>= 1) {
        sq += __shfl_down(sq, off);
        sk += __shfl_down(sk, off);
    }
    __syncthreads();
    if ((t & 63) == 0) { unsafeAtomicAdd(&stats[0], sq); unsafeAtomicAdd(&stats[1], sk); }
    if (t < D) unsafeAtomicAdd(&ksum[t], lks[t]);
}

// ---------------- K2: split-K partials of C = k^T @ vW ----------------
__global__ __launch_bounds__(256) void k_ktv(const float* __restrict__ karr,
                                             const float* __restrict__ vW,
                                             float* __restrict__ part, int M)
{
    __shared__ float ks[4][D];
    __shared__ float vs[4][D];
    const int t = threadIdx.x;
    const int P = (int)gridDim.x;
    const int chunk = (M + P - 1) / P;
    const int rbeg = blockIdx.x * chunk;
    const int rend = min(rbeg + chunk, M);
    const int tj = t & 15, to = t >> 4;
    float acc[4][4];
#pragma unroll
    for (int i = 0; i < 4; ++i)
#pragma unroll
        for (int j = 0; j < 4; ++j) acc[i][j] = 0.f;

    for (int r0 = rbeg; r0 < rend; r0 += 4) {
        const int rr = t >> 6, c = t & 63;
        const int gr = r0 + rr;
        if (c < 32) {
            float4 v4 = make_float4(0.f, 0.f, 0.f, 0.f);
            if (gr < rend) v4 = *(const float4*)(karr + (size_t)gr * D + c * 4);
            *(float4*)(&ks[rr][c * 4]) = v4;
        } else {
            const int cc = c - 32;
            float4 v4 = make_float4(0.f, 0.f, 0.f, 0.f);
            if (gr < rend) v4 = *(const float4*)(vW + (size_t)gr * D + cc * 4);
            *(float4*)(&vs[rr][cc * 4]) = v4;
        }
        __syncthreads();
#pragma unroll
        for (int r2 = 0; r2 < 4; ++r2) {
            const float4 a = *(const float4*)(&ks[r2][4 * tj]);
            const float4 b = *(const float4*)(&vs[r2][4 * to]);
            const float av[4] = {a.x, a.y, a.z, a.w};
            const float bv[4] = {b.x, b.y, b.z, b.w};
#pragma unroll
            for (int jj = 0; jj < 4; ++jj)
#pragma unroll
                for (int oo = 0; oo < 4; ++oo) acc[jj][oo] += av[jj] * bv[oo];
        }
        __syncthreads();
    }
    float* pp = part + (size_t)blockIdx.x * (D * D);
#pragma unroll
    for (int jj = 0; jj < 4; ++jj)
#pragma unroll
        for (int oo = 0; oo < 4; ++oo)
            pp[(size_t)(4 * tj + jj) * D + 4 * to + oo] = acc[jj][oo];
}

__global__ void k_redC(const float* __restrict__ part, float* __restrict__ Craw, int P)
{
    const int e = blockIdx.x * 256 + threadIdx.x; // 16384 total
    float s = 0.f;
    for (int p = 0; p < P; ++p) s += part[(size_t)p * (D * D) + e];
    Craw[e] = s;
}

__global__ void k_scal(const float* __restrict__ ksum, float* __restrict__ stats,
                       float* __restrict__ kq)
{
    const int t = threadIdx.x; // 128
    const float nq = sqrtf(stats[0]);
    const float nk = sqrtf(stats[1]);
    const float inv = 1.0f / (nq * nk * 128.0f);
    kq[t] = ksum[t] * inv;
    if (t == 0) stats[2] = inv;
}

__global__ void k_c3t(const float* __restrict__ Craw, const float* __restrict__ stats,
                      float* __restrict__ C3t)
{
    const int e = blockIdx.x * 256 + threadIdx.x; // 16384, e = o*128 + j
    C3t[e] = Craw[(size_t)(e & 127) * D + (e >> 7)] * stats[2];
}

// per-node attention scale: scale[r] = 0.16 / (1 + q[r].kq)
__global__ __launch_bounds__(256) void k_qk(const float* __restrict__ qarr,
                                            const float* __restrict__ kq,
                                            float* __restrict__ scale, int M)
{
    const int t = threadIdx.x;
    const int r = blockIdx.x * 64 + (t >> 2);
    const int p = t & 3;
    if (r >= M) return;
    const float* row = qarr + (size_t)r * D + p * 32;
    const float* kqp = kq + p * 32;
    float s = 0.f;
#pragma unroll
    for (int i = 0; i < 32; i += 4) {
        const float4 v = *(const float4*)(row + i);
        s += v.x * kqp[i] + v.y * kqp[i + 1] + v.z * kqp[i + 2] + v.w * kqp[i + 3];
    }
    s += __shfl_xor(s, 1);
    s += __shfl_xor(s, 2);
    if (p == 0) scale[r] = 0.16f / (1.0f + s);
}

// ---------------- K4: out = scale*(vW + q@C3^T) + 0.24*xW + bias + u/deg ----------------
__global__ __launch_bounds__(256) void k_final(const float* __restrict__ qarr,
                                               const float* __restrict__ C3t,
                                               const float* __restrict__ vW,
                                               const float* __restrict__ xW,
                                               const float* __restrict__ uarr,
                                               const int* __restrict__ cnt,
                                               const float* __restrict__ scale,
                                               const float* __restrict__ biasout,
                                               float* __restrict__ out, int M)
{
    __shared__ float As[64 * D];
    __shared__ float Bs[64 * D];
    const int t = threadIdx.x;
    const int row0 = blockIdx.x * 64;
    const int col0 = blockIdx.y * 64;

    for (int s = 0; s < 8; ++s) {
        int f = t + 256 * s;
        int r = f >> 5, k0 = (f & 31) << 2;
        int gr = row0 + r; if (gr > M - 1) gr = M - 1;
        *(float4*)(As + swz(r, k0)) = *(const float4*)(qarr + (size_t)gr * D + k0);
    }
    for (int s = 0; s < 8; ++s) {
        int f = t + 256 * s;
        int r = f >> 5, k0 = (f & 31) << 2;
        *(float4*)(Bs + swz(r, k0)) = *(const float4*)(C3t + (size_t)(col0 + r) * D + k0);
    }
    __syncthreads();

    const int tx = t & 15, ty = t >> 4;
    float acc[4][4];
#pragma unroll
    for (int i = 0; i < 4; ++i)
#pragma unroll
        for (int j = 0; j < 4; ++j) acc[i][j] = 0.f;

#pragma unroll 2
    for (int k0 = 0; k0 < D; k0 += 4) {
        float4 a[4], b[4];
#pragma unroll
        for (int i = 0; i < 4; ++i) a[i] = *(const float4*)(As + swz(ty + 16 * i, k0));
#pragma unroll
        for (int j = 0; j < 4; ++j) b[j] = *(const float4*)(Bs + swz(tx + 16 * j, k0));
#pragma unroll
        for (int i = 0; i < 4; ++i) {
            const float av[4] = {a[i].x, a[i].y, a[i].z, a[i].w};
#pragma unroll
            for (int j = 0; j < 4; ++j) {
                acc[i][j] += av[0] * b[j].x + av[1] * b[j].y + av[2] * b[j].z + av[3] * b[j].w;
            }
        }
    }

#pragma unroll
    for (int i = 0; i < 4; ++i) {
        const int r = row0 + ty + 16 * i;
        if (r < M) {
            const float rc = scale[r];
            const float sc = 1.0f / (float)(cnt[r] + 1);
#pragma unroll
            for (int j = 0; j < 4; ++j) {
                const int c = col0 + tx + 16 * j;
                const size_t idx = (size_t)r * D + c;
                out[idx] = rc * (vW[idx] + acc[i][j]) + 0.24f * xW[idx] + biasout[c] + sc * uarr[idx];
            }
        }
    }
}

// ---------------- K5: CSR gather: out[d] += sum_e w_e * u[src_e] ----------------
__global__ __launch_bounds__(256) void k_gather(const int* __restrict__ offs,
                                                const int* __restrict__ cnt,
                                                const int* __restrict__ csrc,
                                                const float* __restrict__ cw,
                                                const float* __restrict__ uarr,
                                                float* __restrict__ out, int M)
{
    const int t = threadIdx.x;
    const int d = blockIdx.x * 2 + (t >> 7);
    if (d >= M) return;
    const int col = t & 127;
    const int end = offs[d]; // offs holds END after k_fill
    const int n = cnt[d];
    float acc = 0.f;
    for (int j = end - n; j < end; ++j) {
        const int s = csrc[j];
        const float w = cw[j];
        acc += w * uarr[(size_t)s * D + col];
    }
    const size_t idx = (size_t)d * D + col;
    out[idx] += acc;
}

extern "C" void kernel_launch(void* const* d_in, const int* in_sizes, int n_in,
                              void* d_out, int out_size, void* d_ws, size_t ws_size,
                              hipStream_t stream)
{
    const float* x  = (const float*)d_in[0];
    const int*   ei = (const int*)d_in[1];
    const float* Wq = (const float*)d_in[2];
    const float* Wk = (const float*)d_in[3];
    const float* Wv = (const float*)d_in[4];
    const float* Wg = (const float*)d_in[5];
    const float* bg = (const float*)d_in[6];
    const float* Wl = (const float*)d_in[7];
    const float* bl = (const float*)d_in[8];

    const int M = in_sizes[0] / D;
    const int E = in_sizes[1] / 2;
    const size_t NQ = (size_t)M * D;
    const int P = 256;

    float* ws      = (float*)d_ws;
    float* q       = ws;                 // [M,128]
    float* karr    = ws + NQ;            // [M,128]
    float* vW      = ws + 2 * NQ;        // [M,128]
    float* xW      = ws + 3 * NQ;        // [M,128]
    float* u       = ws + 4 * NQ;        // [M,128]
    float* scale   = ws + 5 * NQ;        // [M]
    float* dinv    = scale + M;          // [M]
    float* stats   = dinv + M;           // [8]
    float* ksum    = stats + 8;          // [128]
    float* kq      = ksum + D;           // [128]
    float* Craw    = kq + D;             // [128*128]
    float* C3t     = Craw + D * D;       // [128*128]
    float* Bcat    = C3t + D * D;        // [640*128]
    float* biasout = Bcat + 640 * D;     // [128]
    int*   cnt     = (int*)(biasout + D);   // [M]
    int*   offs    = cnt + M;               // [M]
    int*   csrc    = offs + M;              // [E]
    float* cw      = (float*)(csrc + E);    // [E]
    float* part    = cw + E;                // [P*128*128]

    float* out = (float*)d_out;

    // weights + CSR build (independent of GEMM chain)
    k_prep<<<dim3(641), dim3(128), 0, stream>>>(Wq, Wk, Wv, Wg, bg, Wl, bl, Bcat, biasout);
    k_zero<<<1, 256, 0, stream>>>(stats, ksum);
    k_zcnt<<<(M + 255) / 256, 256, 0, stream>>>(cnt, M);
    k_hist<<<(E + 255) / 256, 256, 0, stream>>>(ei + E, cnt, E);
    k_dinv<<<(M + 255) / 256, 256, 0, stream>>>(cnt, dinv, M);
    k_scan<<<1, 1024, 0, stream>>>(cnt, offs, M);
    k_fill<<<(E + 255) / 256, 256, 0, stream>>>(ei, ei + E, dinv, offs, csrc, cw, E);

    // dense chain
    k_gemm5<<<dim3((M + 63) / 64, 10), 256, 0, stream>>>(x, Bcat, q, M, NQ);
    k_stats<<<512, 256, 0, stream>>>(q, karr, stats, ksum, NQ);
    k_ktv<<<P, 256, 0, stream>>>(karr, vW, part, M);
    k_redC<<<64, 256, 0, stream>>>(part, Craw, P);
    k_scal<<<1, 128, 0, stream>>>(ksum, stats, kq);
    k_c3t<<<64, 256, 0, stream>>>(Craw, stats, C3t);
    k_qk<<<(M + 63) / 64, 256, 0, stream>>>(q, kq, scale, M);

    k_final<<<dim3((M + 63) / 64, 2), 256, 0, stream>>>(q, C3t, vW, xW, u, cnt, scale, biasout, out, M);
    k_gather<<<(M + 1) / 2, 256, 0, stream>>>(offs, cnt, csrc, cw, u, out, M);
}

// Round 3
// 379.688 us; speedup vs baseline: 3.9233x; 1.6204x over previous
//
#include <hip/hip_runtime.h>
#include <cstdint>
#include <cstddef>

#define D 128
typedef unsigned short u16;
typedef short bf16x8 __attribute__((ext_vector_type(8)));
typedef float f32x4 __attribute__((ext_vector_type(4)));

// bf16 pack/unpack (RTNE)
__device__ __forceinline__ u16 f2b(float f) {
    uint32_t u = __float_as_uint(f);
    return (u16)((u + 0x7FFFu + ((u >> 16) & 1u)) >> 16);
}
__device__ __forceinline__ float b2f(u16 b) {
    return __uint_as_float(((uint32_t)b) << 16);
}

// XOR swizzle on bf16 k-index within a [rows][128] (or [rows][64]) LDS tile:
// flips k bits 3..5 by row&7 -> byte ^= (row&7)<<4 (16B groups spread across banks)
#define SWZ(r, k) ((k) ^ (((r) & 7) << 3))

// ---------------- K0: fold weights on device -> bf16 Bcat ----------------
// Bcatb[640][128]: rows 0..127   = Wq^T
//                  rows 128..255 = Wk^T
//                  rows 256..383 = (Wv@Wl^T)^T
//                  rows 384..511 = Wl
//                  rows 512..639 = 0.6*(Wl@Wg)
// biasout[o] = bl[o] + 0.6*sum_m bg[m]*Wl[o][m]
__global__ void k_prep(const float* __restrict__ Wq, const float* __restrict__ Wk,
                       const float* __restrict__ Wv, const float* __restrict__ Wg,
                       const float* __restrict__ bg, const float* __restrict__ Wl,
                       const float* __restrict__ bl,
                       u16* __restrict__ Bcatb, float* __restrict__ biasout)
{
    const int b = blockIdx.x;
    const int t = threadIdx.x; // 128
    if (b < 640) {
        const int strip = b >> 7, n = b & 127;
        float val;
        if (strip == 0) {
            val = Wq[t * D + n];
        } else if (strip == 1) {
            val = Wk[t * D + n];
        } else if (strip == 2) {
            float s = 0.f;
            for (int m = 0; m < D; ++m) s += Wv[t * D + m] * Wl[n * D + m];
            val = s;
        } else if (strip == 3) {
            val = Wl[n * D + t];
        } else {
            float s = 0.f;
            for (int m = 0; m < D; ++m) s += Wl[n * D + m] * Wg[m * D + t];
            val = 0.6f * s;
        }
        Bcatb[(size_t)b * D + t] = f2b(val);
    } else {
        float s = 0.f;
        for (int m = 0; m < D; ++m) s += bg[m] * Wl[t * D + m];
        biasout[t] = bl[t] + 0.6f * s;
    }
}

__global__ void k_zero(float* __restrict__ stats, float* __restrict__ ksum)
{
    const int t = threadIdx.x;
    if (t < 8) stats[t] = 0.f;
    if (t < D) ksum[t] = 0.f;
}

__global__ void k_zcnt(int* __restrict__ cnt, int M)
{
    const int i = blockIdx.x * 256 + threadIdx.x;
    if (i < M) cnt[i] = 0;
}

__global__ void k_hist(const int* __restrict__ dst, int* __restrict__ cnt, int E)
{
    const int e = blockIdx.x * 256 + threadIdx.x;
    if (e < E) atomicAdd(&cnt[dst[e]], 1);
}

__global__ void k_dinv(const int* __restrict__ cnt, float* __restrict__ dinv, int M)
{
    const int i = blockIdx.x * 256 + threadIdx.x;
    if (i < M) dinv[i] = rsqrtf((float)(cnt[i] + 1)); // +1 self loop
}

// ---------------- hierarchical exclusive scan ----------------
__global__ __launch_bounds__(1024) void k_scan1(const int* __restrict__ cnt,
                                                int* __restrict__ offs,
                                                int* __restrict__ bsum, int M)
{
    __shared__ int wsum[16];
    const int t = threadIdx.x, lane = t & 63, w = t >> 6;
    const int i = blockIdx.x * 1024 + t;
    const int v = (i < M) ? cnt[i] : 0;
    int s = v;
    for (int off = 1; off < 64; off <<= 1) {
        int n = __shfl_up(s, off);
        if (lane >= off) s += n;
    }
    if (lane == 63) wsum[w] = s;
    __syncthreads();
    if (w == 0) {
        int ss = (lane < 16) ? wsum[lane] : 0;
        for (int off = 1; off < 16; off <<= 1) {
            int n = __shfl_up(ss, off);
            if (lane >= off) ss += n;
        }
        if (lane < 16) wsum[lane] = ss;
    }
    __syncthreads();
    const int woff = (w == 0) ? 0 : wsum[w - 1];
    if (i < M) offs[i] = woff + s - v;
    if (t == 1023) bsum[blockIdx.x] = wsum[15];
}

__global__ void k_scanB(int* __restrict__ bsum, int nb) // 1 block, 64 threads, nb<=64
{
    const int t = threadIdx.x;
    int v = (t < nb) ? bsum[t] : 0;
    int s = v;
    for (int off = 1; off < 64; off <<= 1) {
        int n = __shfl_up(s, off);
        if (t >= off) s += n;
    }
    if (t < nb) bsum[t] = s - v; // exclusive
}

__global__ void k_scan2(const int* __restrict__ bsum, int* __restrict__ offs, int M)
{
    const int i = blockIdx.x * 256 + threadIdx.x;
    if (i < M) offs[i] += bsum[i >> 10];
}

// fill CSR: pos = offs[d]++ (after this kernel offs[d] == segment END)
__global__ void k_fill(const int* __restrict__ src, const int* __restrict__ dst,
                       const float* __restrict__ dinv,
                       int* __restrict__ offs, int* __restrict__ csrc,
                       float* __restrict__ cw, int E)
{
    const int e = blockIdx.x * 256 + threadIdx.x;
    if (e < E) {
        const int s = src[e], d = dst[e];
        const int pos = atomicAdd(&offs[d], 1);
        csrc[pos] = s;
        cw[pos] = dinv[s] * dinv[d];
    }
}

// ---------------- x -> bf16 ----------------
__global__ void k_cvt(const float* __restrict__ x, u16* __restrict__ xb, size_t NQ)
{
    const size_t i = ((size_t)blockIdx.x * 256 + threadIdx.x) * 8;
    if (i >= NQ) return;
    const float4 a = *(const float4*)(x + i);
    const float4 b = *(const float4*)(x + i + 4);
    u16 r[8] = {f2b(a.x), f2b(a.y), f2b(a.z), f2b(a.w),
                f2b(b.x), f2b(b.y), f2b(b.z), f2b(b.w)};
    *(uint4*)(xb + i) = *(const uint4*)r;
}

// ---------------- K1: MFMA xb[M,128] @ Bcatb^T -> 5 bf16 outputs ----------------
__global__ __launch_bounds__(256) void k_gemm5(const u16* __restrict__ xb,
                                               const u16* __restrict__ Bcatb,
                                               u16* __restrict__ outbase,
                                               int M, size_t NQ)
{
    __shared__ u16 As[64 * D];
    __shared__ u16 Bs[64 * D];
    const int t = threadIdx.x;
    const int row0 = blockIdx.x * 64;
    const int n0 = blockIdx.y * 64;

#pragma unroll
    for (int p = 0; p < 4; ++p) {
        const int flat = t + 256 * p; // 1024 chunks of 8 bf16
        const int r = flat >> 4, kg = flat & 15;
        int gr = row0 + r; if (gr > M - 1) gr = M - 1;
        const uint4 v = *(const uint4*)(xb + (size_t)gr * D + kg * 8);
        *(uint4*)(As + r * D + SWZ(r, kg * 8)) = v;
    }
#pragma unroll
    for (int p = 0; p < 4; ++p) {
        const int flat = t + 256 * p;
        const int r = flat >> 4, kg = flat & 15;
        const uint4 v = *(const uint4*)(Bcatb + (size_t)(n0 + r) * D + kg * 8);
        *(uint4*)(Bs + r * D + SWZ(r, kg * 8)) = v;
    }
    __syncthreads();

    const int lane = t & 63, w = t >> 6;
    const int wr = (w >> 1) * 32, wc = (w & 1) * 32;
    const int fr = lane & 15, kg = lane >> 4;

    f32x4 acc[2][2] = {};
#pragma unroll
    for (int ks = 0; ks < 4; ++ks) {
        const int kb = ks * 32 + kg * 8;
        bf16x8 a[2], b[2];
#pragma unroll
        for (int i = 0; i < 2; ++i) {
            const int r = wr + 16 * i + fr;
            a[i] = *(const bf16x8*)(As + r * D + SWZ(r, kb));
        }
#pragma unroll
        for (int j = 0; j < 2; ++j) {
            const int r = wc + 16 * j + fr;
            b[j] = *(const bf16x8*)(Bs + r * D + SWZ(r, kb));
        }
#pragma unroll
        for (int i = 0; i < 2; ++i)
#pragma unroll
            for (int j = 0; j < 2; ++j)
                acc[i][j] = __builtin_amdgcn_mfma_f32_16x16x32_bf16(a[i], b[j], acc[i][j], 0, 0, 0);
    }

    const int mat = n0 >> 7, col0 = n0 & 127;
    u16* outp = outbase + (size_t)mat * NQ;
#pragma unroll
    for (int i = 0; i < 2; ++i) {
#pragma unroll
        for (int reg = 0; reg < 4; ++reg) {
            const int r = row0 + wr + 16 * i + kg * 4 + reg; // C/D: row=(lane>>4)*4+reg
            if (r < M) {
#pragma unroll
                for (int j = 0; j < 2; ++j) {
                    const int c = col0 + wc + 16 * j + fr;   // C/D: col=lane&15
                    outp[(size_t)r * D + c] = f2b(acc[i][j][reg]);
                }
            }
        }
    }
}

// ---------------- K1b: sumsq(q), sumsq(k), colsum(k) (bf16 in) ----------------
__global__ __launch_bounds__(256) void k_stats(const u16* __restrict__ qb,
                                               const u16* __restrict__ kb,
                                               float* __restrict__ stats,
                                               float* __restrict__ ksum, size_t NQ)
{
    __shared__ float lks[D];
    const int t = threadIdx.x;
    if (t < D) lks[t] = 0.f;
    __syncthreads();
    float sq = 0.f, sk = 0.f;
    float kc[8] = {0.f, 0.f, 0.f, 0.f, 0.f, 0.f, 0.f, 0.f};
    const size_t step = (size_t)gridDim.x * 256 * 8; // multiple of 128
    const int cb = (t * 8) & 127;
    for (size_t i = ((size_t)blockIdx.x * 256 + t) * 8; i < NQ; i += step) {
        const uint4 qv = *(const uint4*)(qb + i);
        const uint4 kv = *(const uint4*)(kb + i);
        const u16* qp = (const u16*)&qv;
        const u16* kp = (const u16*)&kv;
#pragma unroll
        for (int jj = 0; jj < 8; ++jj) {
            const float q = b2f(qp[jj]); sq += q * q;
            const float k = b2f(kp[jj]); sk += k * k; kc[jj] += k;
        }
    }
#pragma unroll
    for (int jj = 0; jj < 8; ++jj) atomicAdd(&lks[cb + jj], kc[jj]);
    for (int off = 32; off > 0; off >>= 1) {
        sq += __shfl_down(sq, off);
        sk += __shfl_down(sk, off);
    }
    if ((t & 63) == 0) { unsafeAtomicAdd(&stats[0], sq); unsafeAtomicAdd(&stats[1], sk); }
    __syncthreads();
    if (t < D) unsafeAtomicAdd(&ksum[t], lks[t]);
}

// ---------------- K2: MFMA split-K C = k^T @ vW (contraction over rows) ----------------
__global__ __launch_bounds__(256) void k_ktv(const u16* __restrict__ kb,
                                             const u16* __restrict__ vWb,
                                             float* __restrict__ part, int M)
{
    __shared__ u16 kT[D * 64]; // kT[c][r] = kb[r][c], r-index swizzled
    __shared__ u16 vT[D * 64];
    const int t = threadIdx.x;
    const int P = (int)gridDim.x;
    const int chunk = (M + P - 1) / P;
    const int rbeg = blockIdx.x * chunk;
    const int rend = min(rbeg + chunk, M);

    const int lane = t & 63, w = t >> 6;
    const int fr = lane & 15, kg = lane >> 4;

    f32x4 acc[2][8] = {}; // wave w: output rows w*32..+32, cols 0..127

    for (int r0 = rbeg; r0 < rend; r0 += 64) {
#pragma unroll
        for (int p = 0; p < 4; ++p) {
            const int flat = t + 256 * p; // 1024: 64 rows x 16 col-groups
            const int rr = flat & 63, cg = flat >> 6;
            const int gr = r0 + rr;
            uint4 kv = make_uint4(0, 0, 0, 0), vv = make_uint4(0, 0, 0, 0);
            if (gr < rend) {
                kv = *(const uint4*)(kb + (size_t)gr * D + cg * 8);
                vv = *(const uint4*)(vWb + (size_t)gr * D + cg * 8);
            }
            const u16* kp = (const u16*)&kv;
            const u16* vp = (const u16*)&vv;
#pragma unroll
            for (int jj = 0; jj < 8; ++jj) {
                const int c = cg * 8 + jj;
                const int ri = rr ^ ((c & 7) << 3);
                kT[c * 64 + ri] = kp[jj];
                vT[c * 64 + ri] = vp[jj];
            }
        }
        __syncthreads();
#pragma unroll
        for (int ks = 0; ks < 2; ++ks) {
            const int rb = ks * 32 + kg * 8;
            bf16x8 a[2], b[8];
#pragma unroll
            for (int i = 0; i < 2; ++i) {
                const int m = w * 32 + 16 * i + fr;
                a[i] = *(const bf16x8*)(kT + m * 64 + (rb ^ ((m & 7) << 3)));
            }
#pragma unroll
            for (int j = 0; j < 8; ++j) {
                const int n = 16 * j + fr;
                b[j] = *(const bf16x8*)(vT + n * 64 + (rb ^ ((n & 7) << 3)));
            }
#pragma unroll
            for (int i = 0; i < 2; ++i)
#pragma unroll
                for (int j = 0; j < 8; ++j)
                    acc[i][j] = __builtin_amdgcn_mfma_f32_16x16x32_bf16(a[i], b[j], acc[i][j], 0, 0, 0);
        }
        __syncthreads();
    }
    float* pp = part + (size_t)blockIdx.x * (D * D);
#pragma unroll
    for (int i = 0; i < 2; ++i)
#pragma unroll
        for (int reg = 0; reg < 4; ++reg) {
            const int m = w * 32 + 16 * i + kg * 4 + reg;
#pragma unroll
            for (int j = 0; j < 8; ++j)
                pp[(size_t)m * D + 16 * j + fr] = acc[i][j][reg];
        }
}

__global__ void k_redC(const float* __restrict__ part, float* __restrict__ Craw, int P)
{
    const int e = blockIdx.x * 256 + threadIdx.x; // 16384
    float s = 0.f;
    for (int p = 0; p < P; ++p) s += part[(size_t)p * (D * D) + e];
    Craw[e] = s;
}

__global__ void k_scal(const float* __restrict__ ksum, float* __restrict__ stats,
                       float* __restrict__ kq)
{
    const int t = threadIdx.x; // 128
    const float nq = sqrtf(stats[0]);
    const float nk = sqrtf(stats[1]);
    const float inv = 1.0f / (nq * nk * 128.0f);
    kq[t] = ksum[t] * inv;
    if (t == 0) stats[2] = inv;
}

// C3b[o][j] = Craw[j][o] * inv  (bf16, row-major in j = MFMA-B layout for final)
__global__ void k_c3t(const float* __restrict__ Craw, const float* __restrict__ stats,
                      u16* __restrict__ C3b)
{
    const int e = blockIdx.x * 256 + threadIdx.x; // e = o*128 + j
    C3b[e] = f2b(Craw[(size_t)(e & 127) * D + (e >> 7)] * stats[2]);
}

// per-node attention scale: scale[r] = 0.16 / (1 + q[r].kq)
__global__ __launch_bounds__(256) void k_qk(const u16* __restrict__ qb,
                                            const float* __restrict__ kq,
                                            float* __restrict__ scale, int M)
{
    const int t = threadIdx.x;
    const int r = blockIdx.x * 64 + (t >> 2);
    const int p = t & 3;
    if (r >= M) return;
    const u16* row = qb + (size_t)r * D + p * 32;
    const float* kqp = kq + p * 32;
    float s = 0.f;
#pragma unroll
    for (int i = 0; i < 32; i += 8) {
        const uint4 v = *(const uint4*)(row + i);
        const u16* vp = (const u16*)&v;
#pragma unroll
        for (int jj = 0; jj < 8; ++jj) s += b2f(vp[jj]) * kqp[i + jj];
    }
    s += __shfl_xor(s, 1);
    s += __shfl_xor(s, 2);
    if (p == 0) scale[r] = 0.16f / (1.0f + s);
}

// ---------------- K4: MFMA qb @ C3b^T + epilogue ----------------
__global__ __launch_bounds__(256) void k_final(const u16* __restrict__ qb,
                                               const u16* __restrict__ C3b,
                                               const u16* __restrict__ vWb,
                                               const u16* __restrict__ xWb,
                                               const u16* __restrict__ ub,
                                               const int* __restrict__ cnt,
                                               const float* __restrict__ scale,
                                               const float* __restrict__ biasout,
                                               float* __restrict__ out, int M)
{
    __shared__ u16 As[64 * D];
    __shared__ u16 Bs[D * D];
    const int t = threadIdx.x;
    const int row0 = blockIdx.x * 64;

#pragma unroll
    for (int p = 0; p < 4; ++p) {
        const int flat = t + 256 * p;
        const int r = flat >> 4, kg2 = flat & 15;
        int gr = row0 + r; if (gr > M - 1) gr = M - 1;
        const uint4 v = *(const uint4*)(qb + (size_t)gr * D + kg2 * 8);
        *(uint4*)(As + r * D + SWZ(r, kg2 * 8)) = v;
    }
#pragma unroll
    for (int p = 0; p < 8; ++p) {
        const int flat = t + 256 * p; // 2048 chunks
        const int r = flat >> 4, kg2 = flat & 15;
        const uint4 v = *(const uint4*)(C3b + (size_t)r * D + kg2 * 8);
        *(uint4*)(Bs + r * D + SWZ(r, kg2 * 8)) = v;
    }
    __syncthreads();

    const int lane = t & 63, w = t >> 6;
    const int fr = lane & 15, kg = lane >> 4;

    f32x4 acc[8] = {}; // wave w: rows w*16..+16, cols 0..127
#pragma unroll
    for (int ks = 0; ks < 4; ++ks) {
        const int kb2 = ks * 32 + kg * 8;
        const int r = w * 16 + fr;
        const bf16x8 a = *(const bf16x8*)(As + r * D + SWZ(r, kb2));
#pragma unroll
        for (int j = 0; j < 8; ++j) {
            const int n = 16 * j + fr;
            const bf16x8 b = *(const bf16x8*)(Bs + n * D + SWZ(n, kb2));
            acc[j] = __builtin_amdgcn_mfma_f32_16x16x32_bf16(a, b, acc[j], 0, 0, 0);
        }
    }

#pragma unroll
    for (int reg = 0; reg < 4; ++reg) {
        const int r = row0 + w * 16 + kg * 4 + reg;
        if (r < M) {
            const float rc = scale[r];
            const float sc = 1.0f / (float)(cnt[r] + 1);
#pragma unroll
            for (int j = 0; j < 8; ++j) {
                const int c = 16 * j + fr;
                const size_t idx = (size_t)r * D + c;
                out[idx] = rc * (b2f(vWb[idx]) + acc[j][reg]) + 0.24f * b2f(xWb[idx])
                         + biasout[c] + sc * b2f(ub[idx]);
            }
        }
    }
}

// ---------------- K5: CSR gather: out[d] += sum_e w_e * u[src_e] ----------------
__global__ __launch_bounds__(256) void k_gather(const int* __restrict__ offs,
                                                const int* __restrict__ cnt,
                                                const int* __restrict__ csrc,
                                                const float* __restrict__ cw,
                                                const u16* __restrict__ ub,
                                                float* __restrict__ out, int M)
{
    const int t = threadIdx.x;
    const int d = blockIdx.x * 2 + (t >> 7);
    if (d >= M) return;
    const int col = t & 127;
    const int end = offs[d]; // END after k_fill
    const int n = cnt[d];
    float acc = 0.f;
    for (int j = end - n; j < end; ++j) {
        const int s = csrc[j];
        acc += cw[j] * b2f(ub[(size_t)s * D + col]);
    }
    const size_t idx = (size_t)d * D + col;
    out[idx] += acc;
}

extern "C" void kernel_launch(void* const* d_in, const int* in_sizes, int n_in,
                              void* d_out, int out_size, void* d_ws, size_t ws_size,
                              hipStream_t stream)
{
    const float* x  = (const float*)d_in[0];
    const int*   ei = (const int*)d_in[1];
    const float* Wq = (const float*)d_in[2];
    const float* Wk = (const float*)d_in[3];
    const float* Wv = (const float*)d_in[4];
    const float* Wg = (const float*)d_in[5];
    const float* bg = (const float*)d_in[6];
    const float* Wl = (const float*)d_in[7];
    const float* bl = (const float*)d_in[8];

    const int M = in_sizes[0] / D;
    const int E = in_sizes[1] / 2;
    const size_t NQ = (size_t)M * D;
    const int P = 192;
    const int NB = (M + 1023) / 1024;

    char* base = (char*)d_ws;
    auto alloc = [&](size_t bytes) -> char* {
        char* p = base; base += (bytes + 63) & ~(size_t)63; return p;
    };
    float* part    = (float*)alloc((size_t)P * D * D * 4);
    float* Craw    = (float*)alloc(D * D * 4);
    float* scale   = (float*)alloc((size_t)M * 4);
    float* dinv    = (float*)alloc((size_t)M * 4);
    float* stats   = (float*)alloc(64 * 4);
    float* ksum    = (float*)alloc(D * 4);
    float* kq      = (float*)alloc(D * 4);
    float* biasout = (float*)alloc(D * 4);
    float* cw      = (float*)alloc((size_t)E * 4);
    int*   cnt     = (int*)alloc((size_t)M * 4);
    int*   offs    = (int*)alloc((size_t)M * 4);
    int*   bsum    = (int*)alloc(64 * 4);
    int*   csrc    = (int*)alloc((size_t)E * 4);
    u16*   Bcatb   = (u16*)alloc((size_t)640 * D * 2);
    u16*   C3b     = (u16*)alloc(D * D * 2);
    u16*   xb      = (u16*)alloc(NQ * 2);
    u16*   qb      = (u16*)alloc(NQ * 2); // qb..ub contiguous (NQ*2 % 64 == 0)
    u16*   kb      = (u16*)alloc(NQ * 2);
    u16*   vWb     = (u16*)alloc(NQ * 2);
    u16*   xWb     = (u16*)alloc(NQ * 2);
    u16*   ub      = (u16*)alloc(NQ * 2);
    (void)kb; (void)vWb; (void)xWb;

    float* out = (float*)d_out;

    // weights + CSR build
    k_prep<<<dim3(641), dim3(128), 0, stream>>>(Wq, Wk, Wv, Wg, bg, Wl, bl, Bcatb, biasout);
    k_zero<<<1, 256, 0, stream>>>(stats, ksum);
    k_zcnt<<<(M + 255) / 256, 256, 0, stream>>>(cnt, M);
    k_hist<<<(E + 255) / 256, 256, 0, stream>>>(ei + E, cnt, E);
    k_dinv<<<(M + 255) / 256, 256, 0, stream>>>(cnt, dinv, M);
    k_scan1<<<NB, 1024, 0, stream>>>(cnt, offs, bsum, M);
    k_scanB<<<1, 64, 0, stream>>>(bsum, NB);
    k_scan2<<<(M + 255) / 256, 256, 0, stream>>>(bsum, offs, M);
    k_fill<<<(E + 255) / 256, 256, 0, stream>>>(ei, ei + E, dinv, offs, csrc, cw, E);

    // dense chain (bf16 MFMA)
    k_cvt<<<(int)((NQ / 8 + 255) / 256), 256, 0, stream>>>(x, xb, NQ);
    k_gemm5<<<dim3((M + 63) / 64, 10), 256, 0, stream>>>(xb, Bcatb, qb, M, NQ);
    k_stats<<<512, 256, 0, stream>>>(qb, kb, stats, ksum, NQ);
    k_ktv<<<P, 256, 0, stream>>>(kb, vWb, part, M);
    k_redC<<<64, 256, 0, stream>>>(part, Craw, P);
    k_scal<<<1, 128, 0, stream>>>(ksum, stats, kq);
    k_c3t<<<64, 256, 0, stream>>>(Craw, stats, C3b);
    k_qk<<<(M + 63) / 64, 256, 0, stream>>>(qb, kq, scale, M);

    k_final<<<(M + 63) / 64, 256, 0, stream>>>(qb, C3b, vWb, xWb, ub, cnt, scale, biasout, out, M);
    k_gather<<<(M + 1) / 2, 256, 0, stream>>>(offs, cnt, csrc, cw, ub, out, M);
}

// Round 4
// 308.130 us; speedup vs baseline: 4.8344x; 1.2322x over previous
//
#include <hip/hip_runtime.h>
#include <cstdint>
#include <cstddef>

#define D 128
typedef unsigned short u16;
typedef short bf16x8 __attribute__((ext_vector_type(8)));
typedef float f32x4 __attribute__((ext_vector_type(4)));

// bf16 pack/unpack (RTNE)
__device__ __forceinline__ u16 f2b(float f) {
    uint32_t u = __float_as_uint(f);
    return (u16)((u + 0x7FFFu + ((u >> 16) & 1u)) >> 16);
}
__device__ __forceinline__ float b2f(u16 b) {
    return __uint_as_float(((uint32_t)b) << 16);
}

// XOR swizzle on bf16 k-index within a [rows][128] LDS tile (16B groups)
#define SWZ(r, k) ((k) ^ (((r) & 7) << 3))

// ---------------- K0: fold weights -> bf16 Bcat ----------------
__global__ void k_prep(const float* __restrict__ Wq, const float* __restrict__ Wk,
                       const float* __restrict__ Wv, const float* __restrict__ Wg,
                       const float* __restrict__ bg, const float* __restrict__ Wl,
                       const float* __restrict__ bl,
                       u16* __restrict__ Bcatb, float* __restrict__ biasout)
{
    const int b = blockIdx.x;
    const int t = threadIdx.x; // 128
    if (b < 640) {
        const int strip = b >> 7, n = b & 127;
        float val;
        if (strip == 0) {
            val = Wq[t * D + n];
        } else if (strip == 1) {
            val = Wk[t * D + n];
        } else if (strip == 2) {
            float s = 0.f;
            for (int m = 0; m < D; ++m) s += Wv[t * D + m] * Wl[n * D + m];
            val = s;
        } else if (strip == 3) {
            val = Wl[n * D + t];
        } else {
            float s = 0.f;
            for (int m = 0; m < D; ++m) s += Wl[n * D + m] * Wg[m * D + t];
            val = 0.6f * s;
        }
        Bcatb[(size_t)b * D + t] = f2b(val);
    } else {
        float s = 0.f;
        for (int m = 0; m < D; ++m) s += bg[m] * Wl[t * D + m];
        biasout[t] = bl[t] + 0.6f * s;
    }
}

// zero stats/ksum + cnt in one launch
__global__ void k_init(float* __restrict__ stats, float* __restrict__ ksum,
                       int* __restrict__ cnt, int M)
{
    const int i = blockIdx.x * 256 + threadIdx.x;
    if (i < M) cnt[i] = 0;
    if (blockIdx.x == 0) {
        if (threadIdx.x < 8) stats[threadIdx.x] = 0.f;
        if (threadIdx.x < D) ksum[threadIdx.x] = 0.f;
    }
}

__global__ void k_hist(const int* __restrict__ dst, int* __restrict__ cnt, int E)
{
    const int e = blockIdx.x * 256 + threadIdx.x;
    if (e < E) atomicAdd(&cnt[dst[e]], 1);
}

__global__ void k_dinv(const int* __restrict__ cnt, float* __restrict__ dinv, int M)
{
    const int i = blockIdx.x * 256 + threadIdx.x;
    if (i < M) dinv[i] = rsqrtf((float)(cnt[i] + 1)); // +1 self loop
}

// ---------------- hierarchical exclusive scan ----------------
__global__ __launch_bounds__(1024) void k_scan1(const int* __restrict__ cnt,
                                                int* __restrict__ offs,
                                                int* __restrict__ bsum, int M)
{
    __shared__ int wsum[16];
    const int t = threadIdx.x, lane = t & 63, w = t >> 6;
    const int i = blockIdx.x * 1024 + t;
    const int v = (i < M) ? cnt[i] : 0;
    int s = v;
    for (int off = 1; off < 64; off <<= 1) {
        int n = __shfl_up(s, off);
        if (lane >= off) s += n;
    }
    if (lane == 63) wsum[w] = s;
    __syncthreads();
    if (w == 0) {
        int ss = (lane < 16) ? wsum[lane] : 0;
        for (int off = 1; off < 16; off <<= 1) {
            int n = __shfl_up(ss, off);
            if (lane >= off) ss += n;
        }
        if (lane < 16) wsum[lane] = ss;
    }
    __syncthreads();
    const int woff = (w == 0) ? 0 : wsum[w - 1];
    if (i < M) offs[i] = woff + s - v;
    if (t == 1023) bsum[blockIdx.x] = wsum[15];
}

__global__ void k_scanB(int* __restrict__ bsum, int nb) // 1 block, 64 threads
{
    const int t = threadIdx.x;
    int v = (t < nb) ? bsum[t] : 0;
    int s = v;
    for (int off = 1; off < 64; off <<= 1) {
        int n = __shfl_up(s, off);
        if (t >= off) s += n;
    }
    if (t < nb) bsum[t] = s - v; // exclusive
}

__global__ void k_scan2(const int* __restrict__ bsum, int* __restrict__ offs, int M)
{
    const int i = blockIdx.x * 256 + threadIdx.x;
    if (i < M) offs[i] += bsum[i >> 10];
}

// fill CSR: pos = offs[d]++ (after this kernel offs[d] == segment END)
__global__ void k_fill(const int* __restrict__ src, const int* __restrict__ dst,
                       const float* __restrict__ dinv,
                       int* __restrict__ offs, int* __restrict__ csrc,
                       float* __restrict__ cw, int E)
{
    const int e = blockIdx.x * 256 + threadIdx.x;
    if (e < E) {
        const int s = src[e], d = dst[e];
        const int pos = atomicAdd(&offs[d], 1);
        csrc[pos] = s;
        cw[pos] = dinv[s] * dinv[d];
    }
}

// ---------------- K1: MFMA x[M,128](fp32, converted in-staging) @ Bcatb^T ----------------
__global__ __launch_bounds__(256) void k_gemm5(const float* __restrict__ x,
                                               const u16* __restrict__ Bcatb,
                                               u16* __restrict__ outbase,
                                               int M, size_t NQ)
{
    __shared__ u16 As[64 * D];
    __shared__ u16 Bs[64 * D];
    const int t = threadIdx.x;
    const int row0 = blockIdx.x * 64;
    const int n0 = blockIdx.y * 64;

#pragma unroll
    for (int p = 0; p < 4; ++p) {
        const int flat = t + 256 * p; // 1024 chunks of 8
        const int r = flat >> 4, kg = flat & 15;
        int gr = row0 + r; if (gr > M - 1) gr = M - 1;
        const float4 f0 = *(const float4*)(x + (size_t)gr * D + kg * 8);
        const float4 f1 = *(const float4*)(x + (size_t)gr * D + kg * 8 + 4);
        u16 rr[8] = {f2b(f0.x), f2b(f0.y), f2b(f0.z), f2b(f0.w),
                     f2b(f1.x), f2b(f1.y), f2b(f1.z), f2b(f1.w)};
        *(uint4*)(As + r * D + SWZ(r, kg * 8)) = *(const uint4*)rr;
    }
#pragma unroll
    for (int p = 0; p < 4; ++p) {
        const int flat = t + 256 * p;
        const int r = flat >> 4, kg = flat & 15;
        const uint4 v = *(const uint4*)(Bcatb + (size_t)(n0 + r) * D + kg * 8);
        *(uint4*)(Bs + r * D + SWZ(r, kg * 8)) = v;
    }
    __syncthreads();

    const int lane = t & 63, w = t >> 6;
    const int wr = (w >> 1) * 32, wc = (w & 1) * 32;
    const int fr = lane & 15, kg = lane >> 4;

    f32x4 acc[2][2] = {};
#pragma unroll
    for (int ks = 0; ks < 4; ++ks) {
        const int kb = ks * 32 + kg * 8;
        bf16x8 a[2], b[2];
#pragma unroll
        for (int i = 0; i < 2; ++i) {
            const int r = wr + 16 * i + fr;
            a[i] = *(const bf16x8*)(As + r * D + SWZ(r, kb));
        }
#pragma unroll
        for (int j = 0; j < 2; ++j) {
            const int r = wc + 16 * j + fr;
            b[j] = *(const bf16x8*)(Bs + r * D + SWZ(r, kb));
        }
#pragma unroll
        for (int i = 0; i < 2; ++i)
#pragma unroll
            for (int j = 0; j < 2; ++j)
                acc[i][j] = __builtin_amdgcn_mfma_f32_16x16x32_bf16(a[i], b[j], acc[i][j], 0, 0, 0);
    }

    const int mat = n0 >> 7, col0 = n0 & 127;
    u16* outp = outbase + (size_t)mat * NQ;
#pragma unroll
    for (int i = 0; i < 2; ++i) {
#pragma unroll
        for (int reg = 0; reg < 4; ++reg) {
            const int r = row0 + wr + 16 * i + kg * 4 + reg; // C/D: row=(lane>>4)*4+reg
            if (r < M) {
#pragma unroll
                for (int j = 0; j < 2; ++j) {
                    const int c = col0 + wc + 16 * j + fr;   // C/D: col=lane&15
                    outp[(size_t)r * D + c] = f2b(acc[i][j][reg]);
                }
            }
        }
    }
}

// ---------------- K1b: sumsq(q), sumsq(k), colsum(k) ----------------
__global__ __launch_bounds__(256) void k_stats(const u16* __restrict__ qb,
                                               const u16* __restrict__ kb,
                                               float* __restrict__ stats,
                                               float* __restrict__ ksum, size_t NQ)
{
    __shared__ float lks[D];
    const int t = threadIdx.x;
    if (t < D) lks[t] = 0.f;
    __syncthreads();
    float sq = 0.f, sk = 0.f;
    float kc[8] = {0.f, 0.f, 0.f, 0.f, 0.f, 0.f, 0.f, 0.f};
    const size_t step = (size_t)gridDim.x * 256 * 8;
    const int cb = (t * 8) & 127;
    for (size_t i = ((size_t)blockIdx.x * 256 + t) * 8; i < NQ; i += step) {
        const uint4 qv = *(const uint4*)(qb + i);
        const uint4 kv = *(const uint4*)(kb + i);
        const u16* qp = (const u16*)&qv;
        const u16* kp = (const u16*)&kv;
#pragma unroll
        for (int jj = 0; jj < 8; ++jj) {
            const float q = b2f(qp[jj]); sq += q * q;
            const float k = b2f(kp[jj]); sk += k * k; kc[jj] += k;
        }
    }
#pragma unroll
    for (int jj = 0; jj < 8; ++jj) atomicAdd(&lks[cb + jj], kc[jj]);
    for (int off = 32; off > 0; off >>= 1) {
        sq += __shfl_down(sq, off);
        sk += __shfl_down(sk, off);
    }
    if ((t & 63) == 0) { unsafeAtomicAdd(&stats[0], sq); unsafeAtomicAdd(&stats[1], sk); }
    __syncthreads();
    if (t < D) unsafeAtomicAdd(&ksum[t], lks[t]);
}

// ---------------- K2: MFMA split-K C = k^T @ vW ----------------
__global__ __launch_bounds__(256) void k_ktv(const u16* __restrict__ kb,
                                             const u16* __restrict__ vWb,
                                             float* __restrict__ part, int M)
{
    __shared__ u16 kT[D * 64];
    __shared__ u16 vT[D * 64];
    const int t = threadIdx.x;
    const int P = (int)gridDim.x;
    const int chunk = (M + P - 1) / P;
    const int rbeg = blockIdx.x * chunk;
    const int rend = min(rbeg + chunk, M);

    const int lane = t & 63, w = t >> 6;
    const int fr = lane & 15, kg = lane >> 4;

    f32x4 acc[2][8] = {};

    for (int r0 = rbeg; r0 < rend; r0 += 64) {
#pragma unroll
        for (int p = 0; p < 4; ++p) {
            const int flat = t + 256 * p;
            const int rr = flat & 63, cg = flat >> 6;
            const int gr = r0 + rr;
            uint4 kv = make_uint4(0, 0, 0, 0), vv = make_uint4(0, 0, 0, 0);
            if (gr < rend) {
                kv = *(const uint4*)(kb + (size_t)gr * D + cg * 8);
                vv = *(const uint4*)(vWb + (size_t)gr * D + cg * 8);
            }
            const u16* kp = (const u16*)&kv;
            const u16* vp = (const u16*)&vv;
#pragma unroll
            for (int jj = 0; jj < 8; ++jj) {
                const int c = cg * 8 + jj;
                const int ri = rr ^ ((c & 7) << 3);
                kT[c * 64 + ri] = kp[jj];
                vT[c * 64 + ri] = vp[jj];
            }
        }
        __syncthreads();
#pragma unroll
        for (int ks = 0; ks < 2; ++ks) {
            const int rb = ks * 32 + kg * 8;
            bf16x8 a[2], b[8];
#pragma unroll
            for (int i = 0; i < 2; ++i) {
                const int m = w * 32 + 16 * i + fr;
                a[i] = *(const bf16x8*)(kT + m * 64 + (rb ^ ((m & 7) << 3)));
            }
#pragma unroll
            for (int j = 0; j < 8; ++j) {
                const int n = 16 * j + fr;
                b[j] = *(const bf16x8*)(vT + n * 64 + (rb ^ ((n & 7) << 3)));
            }
#pragma unroll
            for (int i = 0; i < 2; ++i)
#pragma unroll
                for (int j = 0; j < 8; ++j)
                    acc[i][j] = __builtin_amdgcn_mfma_f32_16x16x32_bf16(a[i], b[j], acc[i][j], 0, 0, 0);
        }
        __syncthreads();
    }
    float* pp = part + (size_t)blockIdx.x * (D * D);
#pragma unroll
    for (int i = 0; i < 2; ++i)
#pragma unroll
        for (int reg = 0; reg < 4; ++reg) {
            const int m = w * 32 + 16 * i + kg * 4 + reg;
#pragma unroll
            for (int j = 0; j < 8; ++j)
                pp[(size_t)m * D + 16 * j + fr] = acc[i][j][reg];
        }
}

__global__ void k_redC(const float* __restrict__ part, float* __restrict__ Craw, int P)
{
    const int e = blockIdx.x * 256 + threadIdx.x; // 16384
    float s = 0.f;
    for (int p = 0; p < P; ++p) s += part[(size_t)p * (D * D) + e];
    Craw[e] = s;
}

__global__ void k_scal(const float* __restrict__ ksum, float* __restrict__ stats,
                       float* __restrict__ kq)
{
    const int t = threadIdx.x; // 128
    const float nq = sqrtf(stats[0]);
    const float nk = sqrtf(stats[1]);
    const float inv = 1.0f / (nq * nk * 128.0f);
    kq[t] = ksum[t] * inv;
    if (t == 0) stats[2] = inv;
}

// C3b[o][j] = Craw[j][o] * inv
__global__ void k_c3t(const float* __restrict__ Craw, const float* __restrict__ stats,
                      u16* __restrict__ C3b)
{
    const int e = blockIdx.x * 256 + threadIdx.x; // e = o*128 + j
    C3b[e] = f2b(Craw[(size_t)(e & 127) * D + (e >> 7)] * stats[2]);
}

// ---------------- K4: MFMA qb @ C3b^T + fused qk/scale + epilogue ----------------
__global__ __launch_bounds__(256) void k_final(const u16* __restrict__ qb,
                                               const u16* __restrict__ C3b,
                                               const u16* __restrict__ vWb,
                                               const u16* __restrict__ xWb,
                                               const u16* __restrict__ ub,
                                               const int* __restrict__ cnt,
                                               const float* __restrict__ kq,
                                               const float* __restrict__ biasout,
                                               float* __restrict__ out, int M)
{
    __shared__ u16 As[64 * D];
    __shared__ u16 Bs[D * D];
    __shared__ float scaleS[64];
    const int t = threadIdx.x;
    const int row0 = blockIdx.x * 64;

#pragma unroll
    for (int p = 0; p < 4; ++p) {
        const int flat = t + 256 * p;
        const int r = flat >> 4, kg2 = flat & 15;
        int gr = row0 + r; if (gr > M - 1) gr = M - 1;
        const uint4 v = *(const uint4*)(qb + (size_t)gr * D + kg2 * 8);
        *(uint4*)(As + r * D + SWZ(r, kg2 * 8)) = v;
    }
#pragma unroll
    for (int p = 0; p < 8; ++p) {
        const int flat = t + 256 * p;
        const int r = flat >> 4, kg2 = flat & 15;
        const uint4 v = *(const uint4*)(C3b + (size_t)r * D + kg2 * 8);
        *(uint4*)(Bs + r * D + SWZ(r, kg2 * 8)) = v;
    }
    __syncthreads();

    // fused qk: row r = t>>2, quarter = t&3 covers k = q*32..q*32+31
    {
        const int rr = t >> 2, qq = t & 3;
        float s = 0.f;
#pragma unroll
        for (int i = 0; i < 4; ++i) {
            const int kk = qq * 32 + i * 8;
            const bf16x8 a = *(const bf16x8*)(As + rr * D + SWZ(rr, kk));
            const u16* ap = (const u16*)&a;
#pragma unroll
            for (int jj = 0; jj < 8; ++jj) s += b2f(ap[jj]) * kq[kk + jj];
        }
        s += __shfl_xor(s, 1);
        s += __shfl_xor(s, 2);
        if (qq == 0) scaleS[rr] = 0.16f / (1.0f + s);
    }

    const int lane = t & 63, w = t >> 6;
    const int fr = lane & 15, kg = lane >> 4;

    f32x4 acc[8] = {};
#pragma unroll
    for (int ks = 0; ks < 4; ++ks) {
        const int kb2 = ks * 32 + kg * 8;
        const int r = w * 16 + fr;
        const bf16x8 a = *(const bf16x8*)(As + r * D + SWZ(r, kb2));
#pragma unroll
        for (int j = 0; j < 8; ++j) {
            const int n = 16 * j + fr;
            const bf16x8 b = *(const bf16x8*)(Bs + n * D + SWZ(n, kb2));
            acc[j] = __builtin_amdgcn_mfma_f32_16x16x32_bf16(a, b, acc[j], 0, 0, 0);
        }
    }
    __syncthreads(); // scaleS ready

#pragma unroll
    for (int reg = 0; reg < 4; ++reg) {
        const int rr = w * 16 + kg * 4 + reg;
        const int r = row0 + rr;
        if (r < M) {
            const float rc = scaleS[rr];
            const float sc = 1.0f / (float)(cnt[r] + 1);
#pragma unroll
            for (int j = 0; j < 8; ++j) {
                const int c = 16 * j + fr;
                const size_t idx = (size_t)r * D + c;
                out[idx] = rc * (b2f(vWb[idx]) + acc[j][reg]) + 0.24f * b2f(xWb[idx])
                         + biasout[c] + sc * b2f(ub[idx]);
            }
        }
    }
}

// ---------------- K5: wave-cooperative CSR gather ----------------
// one wave per dst; lane = (edge-slot g in 0..3, col-group sub in 0..15);
// one dwordx4 vmem instr fetches 4 edges' rows; hand-unrolled x2 -> 8 in flight.
__global__ __launch_bounds__(256) void k_gather(const int* __restrict__ offs,
                                                const int* __restrict__ cnt,
                                                const int* __restrict__ csrc,
                                                const float* __restrict__ cw,
                                                const u16* __restrict__ ub,
                                                float* __restrict__ out, int M)
{
    const int t = threadIdx.x;
    const int w = t >> 6, lane = t & 63;
    const int d = blockIdx.x * 4 + w;
    if (d >= M) return;
    const int g = lane >> 4, sub = lane & 15;
    const int end = offs[d]; // END after k_fill
    const int n = cnt[d];
    if (n == 0) return;
    float acc[8] = {};
    for (int j0 = end - n; j0 < end; j0 += 8) {
        const int j1 = j0 + g, j2 = j0 + 4 + g;
        int s1 = 0, s2 = 0;
        float w1 = 0.f, w2 = 0.f;
        if (j1 < end) { s1 = csrc[j1]; w1 = cw[j1]; }
        if (j2 < end) { s2 = csrc[j2]; w2 = cw[j2]; }
        const uint4 r1 = *(const uint4*)(ub + (size_t)s1 * D + sub * 8);
        const uint4 r2 = *(const uint4*)(ub + (size_t)s2 * D + sub * 8);
        const u16* p1 = (const u16*)&r1;
        const u16* p2 = (const u16*)&r2;
#pragma unroll
        for (int i = 0; i < 8; ++i) acc[i] += w1 * b2f(p1[i]) + w2 * b2f(p2[i]);
    }
#pragma unroll
    for (int i = 0; i < 8; ++i) {
        acc[i] += __shfl_xor(acc[i], 16);
        acc[i] += __shfl_xor(acc[i], 32);
    }
    if (g == 0) {
        float* o = out + (size_t)d * D + sub * 8;
        float4 o0 = *(float4*)o, o1 = *(float4*)(o + 4);
        o0.x += acc[0]; o0.y += acc[1]; o0.z += acc[2]; o0.w += acc[3];
        o1.x += acc[4]; o1.y += acc[5]; o1.z += acc[6]; o1.w += acc[7];
        *(float4*)o = o0; *(float4*)(o + 4) = o1;
    }
}

extern "C" void kernel_launch(void* const* d_in, const int* in_sizes, int n_in,
                              void* d_out, int out_size, void* d_ws, size_t ws_size,
                              hipStream_t stream)
{
    const float* x  = (const float*)d_in[0];
    const int*   ei = (const int*)d_in[1];
    const float* Wq = (const float*)d_in[2];
    const float* Wk = (const float*)d_in[3];
    const float* Wv = (const float*)d_in[4];
    const float* Wg = (const float*)d_in[5];
    const float* bg = (const float*)d_in[6];
    const float* Wl = (const float*)d_in[7];
    const float* bl = (const float*)d_in[8];

    const int M = in_sizes[0] / D;
    const int E = in_sizes[1] / 2;
    const size_t NQ = (size_t)M * D;
    const int P = 192;
    const int NB = (M + 1023) / 1024;

    char* base = (char*)d_ws;
    auto alloc = [&](size_t bytes) -> char* {
        char* p = base; base += (bytes + 63) & ~(size_t)63; return p;
    };
    float* part    = (float*)alloc((size_t)P * D * D * 4);
    float* Craw    = (float*)alloc(D * D * 4);
    float* dinv    = (float*)alloc((size_t)M * 4);
    float* stats   = (float*)alloc(64 * 4);
    float* ksum    = (float*)alloc(D * 4);
    float* kq      = (float*)alloc(D * 4);
    float* biasout = (float*)alloc(D * 4);
    float* cw      = (float*)alloc((size_t)E * 4);
    int*   cnt     = (int*)alloc((size_t)M * 4);
    int*   offs    = (int*)alloc((size_t)M * 4);
    int*   bsum    = (int*)alloc(64 * 4);
    int*   csrc    = (int*)alloc((size_t)E * 4);
    u16*   Bcatb   = (u16*)alloc((size_t)640 * D * 2);
    u16*   C3b     = (u16*)alloc(D * D * 2);
    u16*   qb      = (u16*)alloc(NQ * 2);
    u16*   kb      = (u16*)alloc(NQ * 2);
    u16*   vWb     = (u16*)alloc(NQ * 2);
    u16*   xWb     = (u16*)alloc(NQ * 2);
    u16*   ub      = (u16*)alloc(NQ * 2);
    (void)kb; (void)vWb; (void)xWb;

    float* out = (float*)d_out;

    // weights + CSR build
    k_prep<<<dim3(641), dim3(128), 0, stream>>>(Wq, Wk, Wv, Wg, bg, Wl, bl, Bcatb, biasout);
    k_init<<<(M + 255) / 256, 256, 0, stream>>>(stats, ksum, cnt, M);
    k_hist<<<(E + 255) / 256, 256, 0, stream>>>(ei + E, cnt, E);
    k_dinv<<<(M + 255) / 256, 256, 0, stream>>>(cnt, dinv, M);
    k_scan1<<<NB, 1024, 0, stream>>>(cnt, offs, bsum, M);
    k_scanB<<<1, 64, 0, stream>>>(bsum, NB);
    k_scan2<<<(M + 255) / 256, 256, 0, stream>>>(bsum, offs, M);
    k_fill<<<(E + 255) / 256, 256, 0, stream>>>(ei, ei + E, dinv, offs, csrc, cw, E);

    // dense chain (bf16 MFMA)
    k_gemm5<<<dim3((M + 63) / 64, 10), 256, 0, stream>>>(x, Bcatb, qb, M, NQ);
    k_stats<<<512, 256, 0, stream>>>(qb, kb, stats, ksum, NQ);
    k_ktv<<<P, 256, 0, stream>>>(kb, vWb, part, M);
    k_redC<<<64, 256, 0, stream>>>(part, Craw, P);
    k_scal<<<1, 128, 0, stream>>>(ksum, stats, kq);
    k_c3t<<<64, 256, 0, stream>>>(Craw, stats, C3b);

    k_final<<<(M + 63) / 64, 256, 0, stream>>>(qb, C3b, vWb, xWb, ub, cnt, kq, biasout, out, M);
    k_gather<<<(M + 3) / 4, 256, 0, stream>>>(offs, cnt, csrc, cw, ub, out, M);
}